// Round 11
// baseline (328.611 us; speedup 1.0000x reference)
//
#include <hip/hip_runtime.h>
#include <hip/hip_bf16.h>
#include <stdint.h>

#define ALPHA_LO 0.8187307530779818f
#define ALPHA_HI 0.9607894391523232f

#define BATCH 64
#define TT    2000
#define II    512
#define HH    512
#define MM    (BATCH*TT)
#define LCH   50
#define CCH   (TT/LCH)

typedef __bf16 bf16;
typedef bf16  bf16x8 __attribute__((ext_vector_type(8)));
typedef float f32x4  __attribute__((ext_vector_type(4)));

#define GLDS(src, dst) __builtin_amdgcn_global_load_lds( \
    (const __attribute__((address_space(1))) unsigned int*)(src), \
    (__attribute__((address_space(3))) unsigned int*)(dst), 16, 0, 0)

// ---------------- K0: convert + transpose W -> fragment-ordered bf16 image --
// Wbt[ks:8][nt:4][kk:2][jj:8][kq:4][fr:16][e:8]
//   = W[nt*128+jj*16+fr][ks*64+kk*32+kq*8+e]
// Per (ks,nt) the 16 KB chunk IS the LDS B-image -> glds identity copy.
__global__ void k_convW(const float* __restrict__ W, bf16* __restrict__ Wbt) {
    const int t  = blockIdx.x * 256 + threadIdx.x;   // 0..32767
    const int h  = t >> 6;                           // 0..511 (B column)
    const int kb = t & 63;                           // 8-float k group
    const float* src = W + (size_t)h * II + kb * 8;
    f32x4 v0 = *(const f32x4*)(src);
    f32x4 v1 = *(const f32x4*)(src + 4);
    bf16x8 o;
    o[0]=(bf16)v0[0]; o[1]=(bf16)v0[1]; o[2]=(bf16)v0[2]; o[3]=(bf16)v0[3];
    o[4]=(bf16)v1[0]; o[5]=(bf16)v1[1]; o[6]=(bf16)v1[2]; o[7]=(bf16)v1[3];
    const int ks = kb >> 3, kk = (kb >> 2) & 1, kq = kb & 3;
    const int nt = h >> 7, jj = (h >> 4) & 7, fr = h & 15;
    bf16* dst = Wbt + (size_t)ks * 32768 + nt * 8192 + kk * 4096
                    + jj * 512 + kq * 128 + fr * 8;
    *(bf16x8*)dst = o;
}

// ---------------- K1: GEMM  Y[M,H] = X[M,I] * W[H,I]^T  (bf16 MFMA) --------
// 128x128 tile, 4 waves (2m x 2n), wave 64x64, BK=64 -> 8 K-steps.
// A: DIRECT global->reg (lane (fr,kq) reads X[row][kq*8..+8] = the exact A
// fragment), issued ~1 step early in kk-halves; cvt f32->bf16 at use.
// B: glds into 3 LDS bufs, issued at t+2 after the top-of-step barrier.
// B(t) completion is covered by step t-1's per-register cvt wait (in-order
// vmcnt; B(t) was issued before A(t-1).kk1) -> 1 barrier/step, no drains.
// Epilogue: acc -> bf16 -> LDS bounce -> coalesced dwordx4 row stores.
__global__ __launch_bounds__(256, 2) void k_gemm(const float* __restrict__ X,
                                                 const bf16* __restrict__ Wbt,
                                                 bf16* __restrict__ Y) {
    __shared__ bf16 Bl[3 * 8192];    // 48 KB; epilogue bounce reuses it
    const int tid  = threadIdx.x;
    // bijective XCD swizzle (4000 % 8 == 0); 4 n-tiles of an m-tile adjacent
    const int gg   = blockIdx.x;
    const int swz  = (gg & 7) * 500 + (gg >> 3);
    const int m0   = (swz >> 2) * 128;
    const int nt   = swz & 3;
    const int lane = tid & 63;
    const int wv   = tid >> 6;
    const int wm   = wv >> 1;            // m half (0..1)
    const int wn   = wv & 1;             // n half (0..1)
    const int fr   = lane & 15;
    const int kq   = lane >> 4;

    f32x4 acc[4][4] = {};

    // A direct bases: frag i -> row m0 + wm*64 + i*16 + fr, lane k-off kq*8
    const float* abase[4];
    #pragma unroll
    for (int i = 0; i < 4; ++i)
        abase[i] = X + (size_t)(m0 + wm * 64 + i * 16 + fr) * II + kq * 8;

    // B glds: wave wv stages chunks q (src elem off = wv*512+lane*8)
    const bf16* bsrc = Wbt + nt * 8192 + wv * 512 + lane * 8;

    f32x4 ap[2][2][8];   // [t parity][kk half][4 frags x 2]

    #define ISSUE_AH(t_, kk_) do {                                              \
        _Pragma("unroll")                                                       \
        for (int i = 0; i < 4; ++i) {                                           \
            const float* p = abase[i] + (t_) * 64 + (kk_) * 32;                 \
            ap[(t_) & 1][kk_][i * 2]     = *(const f32x4*)(p);                  \
            ap[(t_) & 1][kk_][i * 2 + 1] = *(const f32x4*)(p + 4);              \
        } } while (0)

    #define GLDS_B(t_) do {                                                     \
        const int ub_ = __builtin_amdgcn_readfirstlane(((t_) % 3) * 8192 + wv * 512); \
        _Pragma("unroll")                                                       \
        for (int q = 0; q < 4; ++q)                                             \
            GLDS(bsrc + (size_t)(t_) * 32768 + q * 2048, &Bl[ub_ + q * 2048]);  \
        } while (0)

    // prologue: B(0), B(1), A(0) both halves; retire B(0) (leave 20 in flight)
    GLDS_B(0);
    GLDS_B(1);
    ISSUE_AH(0, 0);
    ISSUE_AH(0, 1);
    asm volatile("s_waitcnt vmcnt(20)" ::: "memory");

    #pragma unroll
    for (int t = 0; t < 8; ++t) {
        __builtin_amdgcn_s_barrier();            // all waves done with step t-1
        asm volatile("" ::: "memory");
        if (t + 2 < 8) GLDS_B(t + 2);            // buf (t+2)%3 free: read at t-1
        // B fragments for this K-step (8 contiguous-1KB ds_read_b128)
        bf16x8 bb[2][4];
        #pragma unroll
        for (int kk = 0; kk < 2; ++kk)
            #pragma unroll
            for (int j = 0; j < 4; ++j)
                bb[kk][j] = *(const bf16x8*)(&Bl[(t % 3) * 8192 + kk * 4096
                                                 + (wn * 4 + j) * 512 + lane * 8]);
        if (t + 1 < 8) ISSUE_AH(t + 1, 0);       // next step's kk0 A-loads
        #pragma unroll
        for (int kk = 0; kk < 2; ++kk) {
            #pragma unroll
            for (int i = 0; i < 4; ++i) {
                f32x4 a0 = ap[t & 1][kk][i * 2], a1 = ap[t & 1][kk][i * 2 + 1];
                bf16x8 af;
                af[0]=(bf16)a0[0]; af[1]=(bf16)a0[1]; af[2]=(bf16)a0[2]; af[3]=(bf16)a0[3];
                af[4]=(bf16)a1[0]; af[5]=(bf16)a1[1]; af[6]=(bf16)a1[2]; af[7]=(bf16)a1[3];
                #pragma unroll
                for (int j = 0; j < 4; ++j)
                    acc[i][j] = __builtin_amdgcn_mfma_f32_16x16x32_bf16(af, bb[kk][j], acc[i][j], 0, 0, 0);
            }
            if (kk == 0 && t + 1 < 8) ISSUE_AH(t + 1, 1);  // kk1 after kk0 freed
        }
    }

    // ---- epilogue: LDS bounce to coalesced bf16 row stores ----
    __builtin_amdgcn_s_barrier();
    asm volatile("" ::: "memory");
    bf16* Cb = Bl;                               // [128][136] stride-padded
    #pragma unroll
    for (int i = 0; i < 4; ++i)
        #pragma unroll
        for (int j = 0; j < 4; ++j)
            #pragma unroll
            for (int r = 0; r < 4; ++r)
                Cb[(wm * 64 + i * 16 + kq * 4 + r) * 136 + wn * 64 + j * 16 + fr]
                    = (bf16)acc[i][j][r];
    asm volatile("s_waitcnt lgkmcnt(0)" ::: "memory");
    __builtin_amdgcn_s_barrier();
    asm volatile("" ::: "memory");
    const int rcol = (tid & 15) * 8;
    #pragma unroll
    for (int rd = 0; rd < 8; ++rd) {
        const int row = rd * 16 + (tid >> 4);
        bf16x8 v = *(const bf16x8*)(&Cb[row * 136 + rcol]);
        *(bf16x8*)(&Y[(size_t)(m0 + row) * HH + nt * 128 + rcol]) = v;
    }
    #undef ISSUE_AH
    #undef GLDS_B
}

// ---------------- K2: per-chunk Horner partial ------------------------------
__global__ void k_chunk(const bf16* __restrict__ Y, const float* __restrict__ alpha,
                        float* __restrict__ P) {
    const int c = blockIdx.x, b = blockIdx.y;
    const int lane = threadIdx.x;
    const int h0 = lane * 8;
    float a[8], p[8];
    #pragma unroll
    for (int k = 0; k < 8; ++k) {
        a[k] = fminf(fmaxf(alpha[h0 + k], ALPHA_LO), ALPHA_HI);
        p[k] = 0.f;
    }
    const bf16* base = Y + ((size_t)b * TT + (size_t)c * LCH) * HH + h0;
    for (int j = 0; j < LCH; ++j) {
        bf16x8 w = *(const bf16x8*)(base + (size_t)j * HH);
        #pragma unroll
        for (int k = 0; k < 8; ++k) p[k] = a[k] * p[k] + (float)w[k];
    }
    float* po = P + ((size_t)c * BATCH + b) * HH + h0;
    #pragma unroll
    for (int k = 0; k < 8; ++k) po[k] = (1.f - a[k]) * p[k];
}

// ---------------- K3: sequential prefix over chunks -------------------------
__global__ void k_prefix(const float* __restrict__ alpha, const float* __restrict__ u0,
                         const float* __restrict__ P, float* __restrict__ V) {
    const int g = blockIdx.x * 256 + threadIdx.x;
    const int h = g & (HH - 1);
    float a = fminf(fmaxf(alpha[h], ALPHA_LO), ALPHA_HI);
    float a2 = a * a, a4 = a2 * a2, a5 = a4 * a;
    float b2 = a5 * a5, b4 = b2 * b2, a25 = b4 * a5;
    float aL = a25 * a25;
    float v = u0[g];
    for (int c = 0; c < CCH; ++c) {
        const size_t idx = (size_t)c * (BATCH * HH) + g;
        V[idx] = v;
        v = aL * v + P[idx];
    }
}

// ---------------- K4: per-chunk softmax accumulate --------------------------
__global__ void k_soft(const bf16* __restrict__ Y, const float* __restrict__ alpha,
                       const float* __restrict__ V, float* __restrict__ OutP) {
    const int c = blockIdx.x, b = blockIdx.y;
    const int lane = threadIdx.x;
    const int h0 = lane * 8;
    float a[8], bt[8], u[8], o[8];
    #pragma unroll
    for (int k = 0; k < 8; ++k) {
        a[k]  = fminf(fmaxf(alpha[h0 + k], ALPHA_LO), ALPHA_HI);
        bt[k] = 1.f - a[k];
        o[k]  = 0.f;
    }
    const float* vb = V + ((size_t)c * BATCH + b) * HH + h0;
    #pragma unroll
    for (int k = 0; k < 8; ++k) u[k] = vb[k];
    const bf16* base = Y + ((size_t)b * TT + (size_t)c * LCH) * HH + h0;
    for (int j = 0; j < LCH; ++j) {
        bf16x8 w = *(const bf16x8*)(base + (size_t)j * HH);
        float e[8], s = 0.f;
        #pragma unroll
        for (int k = 0; k < 8; ++k) {
            u[k] = a[k] * u[k] + bt[k] * (float)w[k];
            e[k] = __expf(u[k]);
            s += e[k];
        }
        #pragma unroll
        for (int off = 32; off >= 1; off >>= 1) s += __shfl_xor(s, off, 64);
        const float inv = 1.f / s;
        #pragma unroll
        for (int k = 0; k < 8; ++k) o[k] += e[k] * inv;
    }
    float* po = OutP + ((size_t)c * BATCH + b) * HH + h0;
    #pragma unroll
    for (int k = 0; k < 8; ++k) po[k] = o[k];
}

// ---------------- K5: reduce chunk partials -> out --------------------------
__global__ void k_reduce(const float* __restrict__ OutP, float* __restrict__ out) {
    const int g = blockIdx.x * 256 + threadIdx.x;
    float s = 0.f;
    for (int c = 0; c < CCH; ++c) s += OutP[(size_t)c * (BATCH * HH) + g];
    out[g] = s;
}

extern "C" void kernel_launch(void* const* d_in, const int* in_sizes, int n_in,
                              void* d_out, int out_size, void* d_ws, size_t ws_size,
                              hipStream_t stream) {
    const float* x     = (const float*)d_in[0];
    const float* W     = (const float*)d_in[1];
    const float* alpha = (const float*)d_in[2];
    const float* u0    = (const float*)d_in[3];
    float* out = (float*)d_out;

    char* ws = (char*)d_ws;
    bf16* Wbt = (bf16*)ws;                                  //   0.5 MB
    bf16* Yx  = (bf16*)(ws + 524288);                       // 131.1 MB
    float* P  = (float*)(ws + 524288 + 131072000);
    float* V  = P + (size_t)CCH * BATCH * HH;
    float* OutP = V + (size_t)CCH * BATCH * HH;

    hipLaunchKernelGGL(k_convW,  dim3(128),          dim3(256), 0, stream, W, Wbt);
    hipLaunchKernelGGL(k_gemm,   dim3(4000),         dim3(256), 0, stream, x, Wbt, Yx);
    hipLaunchKernelGGL(k_chunk,  dim3(CCH, BATCH),   dim3(64),  0, stream, Yx, alpha, P);
    hipLaunchKernelGGL(k_prefix, dim3(BATCH*HH/256), dim3(256), 0, stream, alpha, u0, P, V);
    hipLaunchKernelGGL(k_soft,   dim3(CCH, BATCH),   dim3(64),  0, stream, Yx, alpha, V, OutP);
    hipLaunchKernelGGL(k_reduce, dim3(BATCH*HH/256), dim3(256), 0, stream, OutP, out);
}